// Round 8
// baseline (116.022 us; speedup 1.0000x reference)
//
#include <hip/hip_runtime.h>

// B=4, S=4096, d_model=256, d_k=d_v=64
#define B_    4
#define S_    4096
#define DM    256
#define DK    64
#define NROWS (B_ * S_)        // 16384
#define LOG2E 1.4426950408889634f
// log2(1 + 2^-9): folded into the QK MFMA C-operand so that v_perm truncation
// of P becomes round-half-up; scale alpha cancels in num/den.
#define PACK_BIAS 0.0028151295f

typedef __attribute__((ext_vector_type(8))) short bfrag;   // 8 bf16 (4 VGPRs)
typedef __attribute__((ext_vector_type(4))) float ffrag;   // 4 f32 acc

__device__ __forceinline__ unsigned bf16_rne_hi(float x) {
    unsigned u = __float_as_uint(x);
    return u + 0x7fffu + ((u >> 16) & 1u);
}
__device__ __forceinline__ unsigned short f2bf(float x) {
    return (unsigned short)(bf16_rne_hi(x) >> 16);
}
__device__ __forceinline__ unsigned pack_bf16x2(float lo, float hi) {
    return (bf16_rne_hi(hi) & 0xffff0000u) | (bf16_rne_hi(lo) >> 16);
}

// raw v_exp_f32 (scores bounded: no overflow guards needed)
__device__ __forceinline__ float fast_exp2(float x) {
#if __has_builtin(__builtin_amdgcn_exp2f)
    return __builtin_amdgcn_exp2f(x);
#else
    float r;
    asm("v_exp_f32 %0, %1\n\ts_nop 1" : "=v"(r) : "v"(x));
    return r;
#endif
}

// truncation-pack of two f32 into bf16x2 (1 VALU); inputs pre-scaled by
// (1+2^-9) via the MFMA C bias -> effective round-half-up.
__device__ __forceinline__ unsigned trunc_pack_bf16x2(float lo, float hi) {
    return __builtin_amdgcn_perm(__float_as_uint(hi), __float_as_uint(lo),
                                 0x07060302u);
}

__device__ __forceinline__ void proj_step(
    const float4 xv0, const float4 xv1, const unsigned short* wlds,
    int kf, int m, int quad, ffrag acc[4])
{
    union { bfrag v; unsigned u[4]; } pk;
    pk.u[0] = pack_bf16x2(xv0.x, xv0.y);
    pk.u[1] = pack_bf16x2(xv0.z, xv0.w);
    pk.u[2] = pack_bf16x2(xv1.x, xv1.y);
    pk.u[3] = pack_bf16x2(xv1.z, xv1.w);
#pragma unroll
    for (int dt = 0; dt < 4; ++dt) {
        const bfrag Bf = *(const bfrag*)&wlds[(dt * 16 + m) * 264 + kf * 32 + quad * 8];
        acc[dt] = __builtin_amdgcn_mfma_f32_16x16x32_bf16(pk.v, Bf, acc[dt], 0, 0, 0);
    }
}

// ---------------------------------------------------------------------------
// R8 prep: 512 homogeneous blocks (was 768 heterogeneous = 3 scheduling
// rounds/CU). Each block: (1) one 32-key v-transpose slice (light, hides in
// the proj's load shadow), (2) 64-row projection with ALL 8 x-chunks issued
// upfront (16 float4 in flight covering W-stage + barrier latency).
// ---------------------------------------------------------------------------
__global__ __launch_bounds__(256) void fused_prep(
    const float* __restrict__ q, const float* __restrict__ k,
    const float* __restrict__ v, const float* __restrict__ wq,
    const float* __restrict__ wk, unsigned short* __restrict__ vT,
    unsigned short* __restrict__ qpb, unsigned short* __restrict__ kpb)
{
    __shared__ __align__(16) char smem[64 * 264 * 2];   // 33792 B (union)
    const int blk  = blockIdx.x;                         // 0..511
    const int tid  = threadIdx.x;
    const int lane = tid & 63, w = tid >> 6;
    const int m = lane & 15, quad = lane >> 4;

    // ---- phase 1: v-transpose, one 32-key tile per block ----
    {
        float (*tile)[65] = (float(*)[65])smem;
        const int b = blk >> 7;                 // 0..3
        const int t = blk & 127;                // tile within batch
        const int s0 = t * 32;
#pragma unroll
        for (int i = 0; i < 8; ++i) {
            const int sl = i * 4 + w;           // 0..31
            tile[sl][lane] = v[(b * S_ + s0 + sl) * DK + lane];
        }
        __syncthreads();
        const int hi = lane >> 5, pos = lane & 31;
        const int keyl = (pos & 1) ? (pos >> 1) + 16 : (pos >> 1);
#pragma unroll
        for (int i = 0; i < 8; ++i) {
            const int d = i * 8 + w * 2 + hi;   // 0..63
            vT[((size_t)(b * 128 + t) * 64 + d) * 32 + pos] =
                f2bf(tile[keyl][d]);
        }
        __syncthreads();                        // tile dead before wlds reuse
    }

    // ---- phase 2: projection, 64 rows/block ----
    {
        unsigned short* wlds = (unsigned short*)smem;   // [64][264] bf16
        const int half = blk >> 8, rblk = blk & 255;
        const float* x;
        const float* wsrc;
        unsigned short* o;
        float scale;
        if (half == 0) { x = q; wsrc = wq; o = qpb; scale = 0.125f * LOG2E; }
        else           { x = k; wsrc = wk; o = kpb; scale = 1.0f; }

        const int rows0 = rblk * 64 + w * 16;
        const float* xrow = x + (size_t)(rows0 + m) * DM + quad * 8;
        const float4* xf4 = (const float4*)xrow;

        // issue ALL x loads NOW (16 float4 in flight; land during staging)
        float4 xA[8][2];
#pragma unroll
        for (int t = 0; t < 8; ++t) {
            xA[t][0] = xf4[t * 8];
            xA[t][1] = xf4[t * 8 + 1];
        }

        // stage w (64x256 f32 -> bf16 LDS, stride 264)
#pragma unroll
        for (int i = 0; i < 16; ++i) {
            const int idx4 = i * 256 + tid;             // float4 index, < 4096
            const int r = idx4 >> 6, c4 = idx4 & 63;
            const float4 wv = ((const float4*)wsrc)[idx4];
            uint2 pk;
            pk.x = pack_bf16x2(wv.x, wv.y);
            pk.y = pack_bf16x2(wv.z, wv.w);
            *(uint2*)&wlds[r * 264 + c4 * 4] = pk;
        }
        __syncthreads();

        ffrag acc[4];
#pragma unroll
        for (int dt = 0; dt < 4; ++dt) acc[dt] = (ffrag)(0.0f);

#pragma unroll
        for (int kf = 0; kf < 8; ++kf)
            proj_step(xA[kf][0], xA[kf][1], wlds, kf, m, quad, acc);

#pragma unroll
        for (int dt = 0; dt < 4; ++dt)
#pragma unroll
            for (int r = 0; r < 4; ++r)
                o[(rows0 + quad * 4 + r) * DK + dt * 16 + m] =
                    f2bf(fmaxf(acc[dt][r], 0.0f) * scale);
    }
}

// ---------------------------------------------------------------------------
// Attention — byte-identical to R7 (64 rows/block, 8 waves x 512-key spans).
// ---------------------------------------------------------------------------
__global__ __launch_bounds__(512, 2) void attn_mfma(
    const unsigned short* __restrict__ qp, const unsigned short* __restrict__ kp,
    const unsigned short* __restrict__ vT, float* __restrict__ out)
{
    __shared__ __align__(16) char smem[40960];   // P: 8 waves x 5120B; epilogue reuse
    unsigned short* Plds = (unsigned short*)smem;

    const int tid  = threadIdx.x;
    const int lane = tid & 63, w = tid >> 6;     // w in 0..7
    const int m = lane & 15, quad = lane >> 4;

    // XCD-chunked bijective remap (256 % 8 == 0, chunk = 32)
    const int flat = blockIdx.x;                 // 0..255
    const int qg   = ((flat & 7) << 5) | (flat >> 3);   // 0..255 (64-row groups)

    const int qbase = qg * 64;
    const int b = qg >> 6;
    const int kstart = w * 512;                  // 16 tiles of 32 keys / wave

    bfrag qa[4][2];
#pragma unroll
    for (int mt = 0; mt < 4; ++mt)
#pragma unroll
        for (int kf = 0; kf < 2; ++kf)
            qa[mt][kf] = *(const bfrag*)&qp[(qbase + mt * 16 + m) * DK + kf * 32 + quad * 8];

    ffrag oacc[4][4];
    float dacc[4][4];
#pragma unroll
    for (int mt = 0; mt < 4; ++mt) {
#pragma unroll
        for (int dt = 0; dt < 4; ++dt) oacc[mt][dt] = (ffrag)(0.0f);
#pragma unroll
        for (int r = 0; r < 4; ++r) dacc[mt][r] = 0.0f;
    }

    // stepped base pointers; per-tile offsets are imm-able
    const unsigned short* kptr = kp + ((size_t)b * S_ + kstart + m) * DK + quad * 8;
    const unsigned short* vptr = vT + ((size_t)(b * 128 + (kstart >> 5)) * 64 + m) * 32 + quad * 8;
    unsigned short* Pw = Plds + w * 2560;        // 5120 B per wave: [64][40]

    const ffrag cbias = (ffrag)(PACK_BIAS);

    // preload tile 0 into slot 0
    bfrag kbuf[2][2][2], vbuf[2][4];
#pragma unroll
    for (int kt = 0; kt < 2; ++kt)
#pragma unroll
        for (int kf = 0; kf < 2; ++kf)
            kbuf[0][kt][kf] = *(const bfrag*)(kptr + kt * 1024 + kf * 32);
#pragma unroll
    for (int dt = 0; dt < 4; ++dt)
        vbuf[0][dt] = *(const bfrag*)(vptr + dt * 512);

    bfrag pa0, pa1, pa2, pa3;

#pragma unroll 2
    for (int jj = 0; jj < 16; ++jj) {
        const int p = jj & 1;

        // 1) prefetch K(jj+1) -> kbuf[p^1]
        if (jj < 15) {
            const unsigned short* kn = kptr + (jj + 1) * 2048;
#pragma unroll
            for (int kt = 0; kt < 2; ++kt)
#pragma unroll
                for (int kf = 0; kf < 2; ++kf)
                    kbuf[p ^ 1][kt][kf] = *(const bfrag*)(kn + kt * 1024 + kf * 32);
        }

        // 2) PV(jj-1): pa x V(jj-1) in vbuf[p^1] (dies here)
        if (jj > 0) {
#pragma unroll
            for (int dt = 0; dt < 4; ++dt) {
                oacc[0][dt] = __builtin_amdgcn_mfma_f32_16x16x32_bf16(pa0, vbuf[p ^ 1][dt], oacc[0][dt], 0, 0, 0);
                oacc[1][dt] = __builtin_amdgcn_mfma_f32_16x16x32_bf16(pa1, vbuf[p ^ 1][dt], oacc[1][dt], 0, 0, 0);
                oacc[2][dt] = __builtin_amdgcn_mfma_f32_16x16x32_bf16(pa2, vbuf[p ^ 1][dt], oacc[2][dt], 0, 0, 0);
                oacc[3][dt] = __builtin_amdgcn_mfma_f32_16x16x32_bf16(pa3, vbuf[p ^ 1][dt], oacc[3][dt], 0, 0, 0);
            }
        }

        // 3) prefetch V(jj+1) -> vbuf[p^1] (slot just freed)
        if (jj < 15) {
            const unsigned short* vn = vptr + (jj + 1) * 2048;
#pragma unroll
            for (int dt = 0; dt < 4; ++dt)
                vbuf[p ^ 1][dt] = *(const bfrag*)(vn + dt * 512);
        }

        const bool mask0 = (jj == 0) && (w == 0) && (m == 0);

        // 4a) QK(jj) mt 0-1 on kbuf[p]; exp + den + pack -> LDS
        {
            ffrag s[2][2];
#pragma unroll
            for (int mt = 0; mt < 2; ++mt)
#pragma unroll
                for (int kt = 0; kt < 2; ++kt) {
                    ffrag t = __builtin_amdgcn_mfma_f32_16x16x32_bf16(qa[mt][0], kbuf[p][kt][0], cbias, 0, 0, 0);
                    s[mt][kt] = __builtin_amdgcn_mfma_f32_16x16x32_bf16(qa[mt][1], kbuf[p][kt][1], t, 0, 0, 0);
                }
#pragma unroll
            for (int mt = 0; mt < 2; ++mt)
#pragma unroll
                for (int r = 0; r < 4; ++r) {
                    float e0 = fast_exp2(s[mt][0][r]);
                    float e1 = fast_exp2(s[mt][1][r]);
                    if (mask0) e0 = 0.0f;
                    dacc[mt][r] += e0 + e1;
                    *(unsigned*)&Pw[(mt * 16 + quad * 4 + r) * 40 + m * 2] =
                        trunc_pack_bf16x2(e0, e1);
                }
        }
        // 4b) QK(jj) mt 2-3; exp + den + pack -> LDS
        {
            ffrag s[2][2];
#pragma unroll
            for (int mt = 2; mt < 4; ++mt)
#pragma unroll
                for (int kt = 0; kt < 2; ++kt) {
                    ffrag t = __builtin_amdgcn_mfma_f32_16x16x32_bf16(qa[mt][0], kbuf[p][kt][0], cbias, 0, 0, 0);
                    s[mt - 2][kt] = __builtin_amdgcn_mfma_f32_16x16x32_bf16(qa[mt][1], kbuf[p][kt][1], t, 0, 0, 0);
                }
#pragma unroll
            for (int mt = 2; mt < 4; ++mt)
#pragma unroll
                for (int r = 0; r < 4; ++r) {
                    float e0 = fast_exp2(s[mt - 2][0][r]);
                    float e1 = fast_exp2(s[mt - 2][1][r]);
                    if (mask0) e0 = 0.0f;
                    dacc[mt][r] += e0 + e1;
                    *(unsigned*)&Pw[(mt * 16 + quad * 4 + r) * 40 + m * 2] =
                        trunc_pack_bf16x2(e0, e1);
                }
        }

        // 5) read P(jj) as A-frags (per-wave DS in-order)
        pa0 = *(const bfrag*)&Pw[(m) * 40 + quad * 8];
        pa1 = *(const bfrag*)&Pw[(16 + m) * 40 + quad * 8];
        pa2 = *(const bfrag*)&Pw[(32 + m) * 40 + quad * 8];
        pa3 = *(const bfrag*)&Pw[(48 + m) * 40 + quad * 8];
    }
    // final PV (tile 15): V(15) is in vbuf[1] (loop count even)
#pragma unroll
    for (int dt = 0; dt < 4; ++dt) {
        oacc[0][dt] = __builtin_amdgcn_mfma_f32_16x16x32_bf16(pa0, vbuf[1][dt], oacc[0][dt], 0, 0, 0);
        oacc[1][dt] = __builtin_amdgcn_mfma_f32_16x16x32_bf16(pa1, vbuf[1][dt], oacc[1][dt], 0, 0, 0);
        oacc[2][dt] = __builtin_amdgcn_mfma_f32_16x16x32_bf16(pa2, vbuf[1][dt], oacc[2][dt], 0, 0, 0);
        oacc[3][dt] = __builtin_amdgcn_mfma_f32_16x16x32_bf16(pa3, vbuf[1][dt], oacc[3][dt], 0, 0, 0);
    }

    // den: reduce over the 16 key-lanes within each quad group
#pragma unroll
    for (int mt = 0; mt < 4; ++mt)
#pragma unroll
        for (int r = 0; r < 4; ++r) {
            float d = dacc[mt][r];
            d += __shfl_xor(d, 1, 64);
            d += __shfl_xor(d, 2, 64);
            d += __shfl_xor(d, 4, 64);
            d += __shfl_xor(d, 8, 64);
            dacc[mt][r] = d;
        }

    // 8-wave tree reduce, two mt-halves (chunk = 2560 f32/wave)
    float* red = (float*)smem;                   // red_i = red + i*2560
#pragma unroll
    for (int half = 0; half < 2; ++half) {
        const int mt0 = half * 2;
        __syncthreads();
        if (w >= 4) {
            float* dst = red + (w - 4) * 2560;
#pragma unroll
            for (int mr = 0; mr < 2; ++mr) {
#pragma unroll
                for (int dt = 0; dt < 4; ++dt)
#pragma unroll
                    for (int r = 0; r < 4; ++r)
                        dst[((mr * 4 + dt) * 4 + r) * 64 + lane] = oacc[mt0 + mr][dt][r];
#pragma unroll
                for (int r = 0; r < 4; ++r)
                    dst[2048 + (mr * 4 + r) * 64 + lane] = dacc[mt0 + mr][r];
            }
        }
        __syncthreads();
        if (w < 4) {
            const float* src = red + w * 2560;
#pragma unroll
            for (int mr = 0; mr < 2; ++mr) {
#pragma unroll
                for (int dt = 0; dt < 4; ++dt)
#pragma unroll
                    for (int r = 0; r < 4; ++r)
                        oacc[mt0 + mr][dt][r] += src[((mr * 4 + dt) * 4 + r) * 64 + lane];
#pragma unroll
                for (int r = 0; r < 4; ++r)
                    dacc[mt0 + mr][r] += src[2048 + (mr * 4 + r) * 64 + lane];
            }
        }
        __syncthreads();
        if (w >= 2 && w < 4) {
            float* dst = red + (w - 2) * 2560;
#pragma unroll
            for (int mr = 0; mr < 2; ++mr) {
#pragma unroll
                for (int dt = 0; dt < 4; ++dt)
#pragma unroll
                    for (int r = 0; r < 4; ++r)
                        dst[((mr * 4 + dt) * 4 + r) * 64 + lane] = oacc[mt0 + mr][dt][r];
#pragma unroll
                for (int r = 0; r < 4; ++r)
                    dst[2048 + (mr * 4 + r) * 64 + lane] = dacc[mt0 + mr][r];
            }
        }
        __syncthreads();
        if (w < 2) {
            const float* src = red + w * 2560;
#pragma unroll
            for (int mr = 0; mr < 2; ++mr) {
#pragma unroll
                for (int dt = 0; dt < 4; ++dt)
#pragma unroll
                    for (int r = 0; r < 4; ++r)
                        oacc[mt0 + mr][dt][r] += src[((mr * 4 + dt) * 4 + r) * 64 + lane];
#pragma unroll
                for (int r = 0; r < 4; ++r)
                    dacc[mt0 + mr][r] += src[2048 + (mr * 4 + r) * 64 + lane];
            }
        }
        __syncthreads();
        if (w == 1) {
#pragma unroll
            for (int mr = 0; mr < 2; ++mr) {
#pragma unroll
                for (int dt = 0; dt < 4; ++dt)
#pragma unroll
                    for (int r = 0; r < 4; ++r)
                        red[((mr * 4 + dt) * 4 + r) * 64 + lane] = oacc[mt0 + mr][dt][r];
#pragma unroll
                for (int r = 0; r < 4; ++r)
                    red[2048 + (mr * 4 + r) * 64 + lane] = dacc[mt0 + mr][r];
            }
        }
        __syncthreads();
        if (w == 0) {
#pragma unroll
            for (int mr = 0; mr < 2; ++mr) {
                const int mt = mt0 + mr;
                float invd[4];
#pragma unroll
                for (int r = 0; r < 4; ++r) {
                    const float dv = dacc[mt][r] + red[2048 + (mr * 4 + r) * 64 + lane];
                    invd[r] = 1.0f / dv;
                }
#pragma unroll
                for (int dt = 0; dt < 4; ++dt)
#pragma unroll
                    for (int r = 0; r < 4; ++r) {
                        const float nv = oacc[mt][dt][r] + red[((mr * 4 + dt) * 4 + r) * 64 + lane];
                        out[(size_t)(qbase + mt * 16 + quad * 4 + r) * DK + dt * 16 + m] =
                            nv * invd[r];
                    }
            }
        }
    }
}

// ---------------------------------------------------------------------------
extern "C" void kernel_launch(void* const* d_in, const int* in_sizes, int n_in,
                              void* d_out, int out_size, void* d_ws, size_t ws_size,
                              hipStream_t stream)
{
    const float* q  = (const float*)d_in[0];
    const float* k  = (const float*)d_in[1];
    const float* v  = (const float*)d_in[2];
    const float* wq = (const float*)d_in[3];
    const float* wk = (const float*)d_in[4];
    float* out = (float*)d_out;

    // ws: qpb 2M | kpb 2M | vT 2M
    char* p = (char*)d_ws;
    unsigned short* qpb = (unsigned short*)p;   p += (size_t)NROWS * DK * 2;
    unsigned short* kpb = (unsigned short*)p;   p += (size_t)NROWS * DK * 2;
    unsigned short* vT  = (unsigned short*)p;

    fused_prep<<<512, 256, 0, stream>>>(q, k, v, wq, wk, vT, qpb, kpb);
    attn_mfma<<<256, 512, 0, stream>>>(qpb, kpb, vT, out);
}